// Round 4
// baseline (139.235 us; speedup 1.0000x reference)
//
#include <hip/hip_runtime.h>
#include <hip/hip_bf16.h>

#define THREADS 1024
#define ROWS 128

typedef __attribute__((ext_vector_type(4))) float f32x4;
typedef __attribute__((ext_vector_type(8))) short s16x8;

__device__ __forceinline__ unsigned short bfbits(float f) {
  __bf16 h = (__bf16)f;
  return __builtin_bit_cast(unsigned short, h);
}
__device__ __forceinline__ float bf2f(unsigned short h) {
  unsigned u = ((unsigned)h) << 16;
  return __builtin_bit_cast(float, u);
}

// ---------------- prep: pack weights into MFMA A-fragment order (bf16) ----------------
// A-frag for mfma_f32_16x16x32_bf16: lane l holds A[m=l&15][k=(l>>4)*8+j], j=0..7
// w1f: [c:12][ft:32][lane:64][8]   (K=384 of W1; k=384 is a rank-1 term in epilogue 1)
// w2f: [c:16][ft:16][lane:64][8]
// w3f: [c: 8][ft:12][lane:64][8]
// whT: [head:128][fo:24][j:16][8] bf16  (head gathers 256B-contiguous per 16-lane group)
__global__ void prep_kernel(const float* __restrict__ W1, const float* __restrict__ W2,
                            const float* __restrict__ W3, const float* __restrict__ Wh,
                            unsigned short* __restrict__ w1f, unsigned short* __restrict__ w2f,
                            unsigned short* __restrict__ w3f, unsigned short* __restrict__ whT) {
  int u = blockIdx.x * blockDim.x + threadIdx.x;
  const int U1 = 24576, U2 = 16384, U3 = 6144, U4 = 49152;
  if (u < U1) {                                   // W1 frags
    int lane = u & 63, r = (u >> 6) & 31, c = u >> 11;
    int f  = r * 16 + (lane & 15);
    int kb = c * 32 + ((lane >> 4) << 3);
    s16x8 v;
    #pragma unroll
    for (int j = 0; j < 8; ++j) v[j] = (short)bfbits(W1[(kb + j) * 512 + f]);
    *(s16x8*)(w1f + (u << 3)) = v;
    return;
  }
  u -= U1;
  if (u < U2) {                                   // W2 frags
    int lane = u & 63, r = (u >> 6) & 15, c = u >> 10;
    int f  = r * 16 + (lane & 15);
    int kb = c * 32 + ((lane >> 4) << 3);
    s16x8 v;
    #pragma unroll
    for (int j = 0; j < 8; ++j) v[j] = (short)bfbits(W2[(kb + j) * 256 + f]);
    *(s16x8*)(w2f + (u << 3)) = v;
    return;
  }
  u -= U2;
  if (u < U3) {                                   // W3 frags
    int lane = u & 63, t = u >> 6;
    int c = t / 12, r = t - c * 12;
    int f  = r * 16 + (lane & 15);
    int kb = c * 32 + ((lane >> 4) << 3);
    s16x8 v;
    #pragma unroll
    for (int j = 0; j < 8; ++j) v[j] = (short)bfbits(W3[(kb + j) * 192 + f]);
    *(s16x8*)(w3f + (u << 3)) = v;
    return;
  }
  u -= U3;
  if (u < U4) {                                   // Wh -> [head][fo][j][8]
    int j = u & 15, v2 = u >> 4;
    int fo = v2 % 24, head = v2 / 24;
    s16x8 v;
    #pragma unroll
    for (int i = 0; i < 8; ++i) v[i] = (short)bfbits(Wh[(fo * 8 + i) * 2048 + head * 16 + j]);
    *(s16x8*)(whT + u * 8) = v;
  }
}

// ---------------- fused MLP: 128 rows/block, 1024 threads, f-outer GEMM1 ----------------
// LDS (163840 B, exactly the 160 KiB pool):
//   xall @ 0     : 98304  (12 chunks x [bt:8][lane':64][16B] bf16 frags, swizzled)
//   h1f  @ 98304 : 65536  (one 256-f half of h1 as GEMM2 B-frags [c2:8][bt:8][lane'][16B])
//   h2f  @ 0     : 65536  (GEMM3 B-frags, aliases xall after GEMM1 done)
//   h3b  @ 98304 : 51200  ([128 rows][200 f] bf16, aliases h1f after GEMM2 done)
// Biases / W1[384][:] / x[:,384] are read straight from global (L1/L2-hot).
#define MFMA(a, b, c) __builtin_amdgcn_mfma_f32_16x16x32_bf16((a), (b), (c), 0, 0, 0)
#define SWZ(lp) (((lp) * 16) ^ ((((lp) >> 4) & 3) << 5))

#define G1_RANGE(P, C0, C1)                                                          \
  _Pragma("unroll")                                                                  \
  for (int c = (C0); c < (C1); ++c) {                                                \
    s16x8 af = *(const s16x8*)(w1f + (((c * 32 + (P) * 16 + w) * 64 + lane) << 3));  \
    _Pragma("unroll")                                                                \
    for (int bt = 0; bt < 8; ++bt) {                                                 \
      s16x8 bfr = *(const s16x8*)(xall + (c << 13) + (bt << 10) + swz_l);            \
      acc1[bt] = MFMA(af, bfr, acc1[bt]);                                            \
    }                                                                                \
  }

__global__ __launch_bounds__(THREADS, 4)
void fused_mlp(const float* __restrict__ x,
               const float* __restrict__ b1,
               const float* __restrict__ b2,
               const float* __restrict__ b3,
               const float* __restrict__ bh,
               const float* __restrict__ W1,
               const int* __restrict__ qid,
               const int* __restrict__ corr,
               const unsigned short* __restrict__ w1f,
               const unsigned short* __restrict__ w2f,
               const unsigned short* __restrict__ w3f,
               const unsigned short* __restrict__ whT,
               float* __restrict__ out) {
  __shared__ __align__(16) unsigned char lds[163840];
  unsigned char*  xall = lds;                             // GEMM1 B-frags (12 chunks)
  unsigned char*  h1f  = lds + 98304;                     // GEMM2 B-frags (one half)
  unsigned char*  h2f  = lds;                             // GEMM3 B-frags (alias xall)
  unsigned short* h3b  = (unsigned short*)(lds + 98304);  // [128][200] bf16 (alias h1f)

  const int tid  = threadIdx.x;
  const int lane = tid & 63;
  const int w    = tid >> 6;     // wave 0..15
  const int b0   = blockIdx.x * ROWS;
  const int l15  = lane & 15;
  const int lh   = lane >> 4;    // 0..3
  const int swz_l = SWZ(lane);

  // prefetch head routing + x[:,384] column (reused by both epilogue-1 passes)
  const int hrow = tid >> 4, hj = tid & 15;
  const int head0 = qid[b0 + hrow] * 2 + corr[b0 + hrow];
  const int head1 = qid[b0 + 64 + hrow] * 2 + corr[b0 + 64 + hrow];
  float xv384[8];
  #pragma unroll
  for (int bt = 0; bt < 8; ++bt)
    xv384[bt] = x[(size_t)(b0 + bt * 16 + l15) * 385 + 384];

  // ---- x staging: group g = chunks 4g..4g+3; 2 frags (16B) per thread per group ----
  f32x4 sv[2][2];
  int s_ad[2];
  auto sload = [&](int g) {
    #pragma unroll
    for (int q = 0; q < 2; ++q) {
      int fi = q * 1024 + tid;
      int c  = (g << 2) + (fi >> 9);
      int wi = fi & 511;
      int bt = wi >> 6, lp = wi & 63;
      int row = (bt << 4) + (lp & 15);
      int k   = c * 32 + ((lp >> 4) << 3);
      const float* p = x + (size_t)(b0 + row) * 385 + k;
      sv[q][0] = *(const f32x4*)p;
      sv[q][1] = *(const f32x4*)(p + 4);
      s_ad[q] = (c << 13) + (bt << 10) + SWZ(lp);
    }
  };
  auto swrite = [&]() {
    #pragma unroll
    for (int q = 0; q < 2; ++q) {
      s16x8 v;
      v[0] = (short)bfbits(sv[q][0][0]); v[1] = (short)bfbits(sv[q][0][1]);
      v[2] = (short)bfbits(sv[q][0][2]); v[3] = (short)bfbits(sv[q][0][3]);
      v[4] = (short)bfbits(sv[q][1][0]); v[5] = (short)bfbits(sv[q][1][1]);
      v[6] = (short)bfbits(sv[q][1][2]); v[7] = (short)bfbits(sv[q][1][3]);
      *(s16x8*)(xall + s_ad[q]) = v;
    }
  };

  f32x4 acc1[8], acc2[8];
  #pragma unroll
  for (int bt = 0; bt < 8; ++bt) { acc1[bt] = (f32x4)0.0f; acc2[bt] = (f32x4)0.0f; }

  // epilogue 1 (pass P): rank-1 + bias + relu -> bf16 frags -> h1f; reset acc1
  auto epi1 = [&](int P) {
    int fg = P * 256 + w * 16 + lh * 4;
    f32x4 bv = *(const f32x4*)(b1 + fg);
    f32x4 wv = *(const f32x4*)(W1 + 384 * 512 + fg);
    int so = ((w >> 1) << 13) + SWZ(l15 + (((2 * w + (lh >> 1)) & 3) << 4)) + ((lh & 1) << 3);
    #pragma unroll
    for (int bt = 0; bt < 8; ++bt) {
      float xv = xv384[bt];
      float v0 = fmaxf(acc1[bt][0] + bv[0] + wv[0] * xv, 0.f);
      float v1 = fmaxf(acc1[bt][1] + bv[1] + wv[1] * xv, 0.f);
      float v2 = fmaxf(acc1[bt][2] + bv[2] + wv[2] * xv, 0.f);
      float v3 = fmaxf(acc1[bt][3] + bv[3] + wv[3] * xv, 0.f);
      unsigned plo = (unsigned)bfbits(v0) | ((unsigned)bfbits(v1) << 16);
      unsigned phi = (unsigned)bfbits(v2) | ((unsigned)bfbits(v3) << 16);
      unsigned long long pk = (unsigned long long)plo | ((unsigned long long)phi << 32);
      *(unsigned long long*)(h1f + so + (bt << 10)) = pk;
      acc1[bt] = (f32x4)0.0f;
    }
  };

  // GEMM2 half: K-chunks c0..c0+7 (h1f holds exactly these 8 chunks)
  auto g2half = [&](int c0) {
    #pragma unroll
    for (int ci = 0; ci < 8; ++ci) {
      int c = c0 + ci;
      s16x8 a2 = *(const s16x8*)(w2f + (((c * 16 + w) * 64 + lane) << 3));
      #pragma unroll
      for (int bt = 0; bt < 8; ++bt) {
        s16x8 bfr = *(const s16x8*)(h1f + (ci << 13) + (bt << 10) + swz_l);
        acc2[bt] = MFMA(a2, bfr, acc2[bt]);
      }
    }
  };

  // ---- phase pipeline ----
  sload(0); swrite();
  __syncthreads();                       // B1: chunks 0..3 staged

  sload(1);
  G1_RANGE(0, 0, 4)
  swrite();
  __syncthreads();                       // B2: chunks 4..7 staged

  sload(2);
  G1_RANGE(0, 4, 8)
  swrite();
  __syncthreads();                       // B3: chunks 8..11 staged

  G1_RANGE(0, 8, 12)
  epi1(0);
  __syncthreads();                       // B4: h1f (f 0..255) ready

  g2half(0);
  __syncthreads();                       // B5: h1f consumed

  G1_RANGE(1, 0, 12)
  epi1(1);
  __syncthreads();                       // B6: h1f (f 256..511) ready

  g2half(8);
  // epilogue 2 -> h2f (xall region; xall dead since pass-B reads ended at B6)
  {
    int fg = w * 16 + lh * 4;
    f32x4 bv = *(const f32x4*)(b2 + fg);
    int so = ((w >> 1) << 13) + SWZ(l15 + (((2 * w + (lh >> 1)) & 3) << 4)) + ((lh & 1) << 3);
    #pragma unroll
    for (int bt = 0; bt < 8; ++bt) {
      float v0 = fmaxf(acc2[bt][0] + bv[0], 0.f);
      float v1 = fmaxf(acc2[bt][1] + bv[1], 0.f);
      float v2 = fmaxf(acc2[bt][2] + bv[2], 0.f);
      float v3 = fmaxf(acc2[bt][3] + bv[3], 0.f);
      unsigned plo = (unsigned)bfbits(v0) | ((unsigned)bfbits(v1) << 16);
      unsigned phi = (unsigned)bfbits(v2) | ((unsigned)bfbits(v3) << 16);
      unsigned long long pk = (unsigned long long)plo | ((unsigned long long)phi << 32);
      *(unsigned long long*)(h2f + so + (bt << 10)) = pk;
    }
  }
  __syncthreads();                       // B7: h2f ready

  // ---------------- GEMM3: h3^T[192f x 128b] = W3^T h2^T, K=256 (waves 0..11) ----------------
  if (w < 12) {
    f32x4 acc3[8];
    #pragma unroll
    for (int bt = 0; bt < 8; ++bt) acc3[bt] = (f32x4)0.0f;
    #pragma unroll
    for (int c = 0; c < 8; ++c) {
      s16x8 a3 = *(const s16x8*)(w3f + (((c * 12 + w) * 64 + lane) << 3));
      #pragma unroll
      for (int bt = 0; bt < 8; ++bt) {
        s16x8 bfr = *(const s16x8*)(h2f + (c << 13) + (bt << 10) + swz_l);
        acc3[bt] = MFMA(a3, bfr, acc3[bt]);
      }
    }
    // epilogue 3 -> h3b [128][200] bf16 (h1f region, dead since B7)
    int fg = w * 16 + lh * 4;
    f32x4 bv = *(const f32x4*)(b3 + fg);
    #pragma unroll
    for (int bt = 0; bt < 8; ++bt) {
      int row = (bt << 4) + l15;
      float v0 = fmaxf(acc3[bt][0] + bv[0], 0.f);
      float v1 = fmaxf(acc3[bt][1] + bv[1], 0.f);
      float v2 = fmaxf(acc3[bt][2] + bv[2], 0.f);
      float v3 = fmaxf(acc3[bt][3] + bv[3], 0.f);
      unsigned plo = (unsigned)bfbits(v0) | ((unsigned)bfbits(v1) << 16);
      unsigned phi = (unsigned)bfbits(v2) | ((unsigned)bfbits(v3) << 16);
      unsigned long long pk = (unsigned long long)plo | ((unsigned long long)phi << 32);
      *(unsigned long long*)((unsigned char*)h3b + row * 400 + w * 32 + lh * 8) = pk;
    }
  }
  __syncthreads();                       // B8: h3b ready

  // ---------------- head: 2 outputs/thread ----------------
  #pragma unroll
  for (int q = 0; q < 2; ++q) {
    int row  = q * 64 + hrow;
    int head = q ? head1 : head0;
    const unsigned short* wp = whT + ((head * 24) * 16 + hj) * 8;
    const unsigned short* hp = h3b + row * 200;
    float acc = bh[(head << 4) + hj];
    #pragma unroll 6
    for (int fo = 0; fo < 24; ++fo) {
      s16x8 wv = *(const s16x8*)(wp + fo * 128);
      s16x8 hv = *(const s16x8*)(hp + fo * 8);
      #pragma unroll
      for (int e = 0; e < 8; ++e)
        acc += bf2f((unsigned short)wv[e]) * bf2f((unsigned short)hv[e]);
    }
    out[(size_t)(b0 + row) * 16 + hj] = acc;
  }
}

extern "C" void kernel_launch(void* const* d_in, const int* in_sizes, int n_in,
                              void* d_out, int out_size, void* d_ws, size_t ws_size,
                              hipStream_t stream) {
  (void)in_sizes; (void)n_in; (void)out_size; (void)ws_size;
  const float* x  = (const float*)d_in[0];
  const float* W1 = (const float*)d_in[1];
  const float* b1 = (const float*)d_in[2];
  const float* W2 = (const float*)d_in[3];
  const float* b2 = (const float*)d_in[4];
  const float* W3 = (const float*)d_in[5];
  const float* b3 = (const float*)d_in[6];
  const float* Wh = (const float*)d_in[7];
  const float* bh = (const float*)d_in[8];
  const int* qid  = (const int*)d_in[9];
  const int* corr = (const int*)d_in[10];
  float* out = (float*)d_out;

  unsigned short* w1f = (unsigned short*)d_ws;     // 196608 bf16
  unsigned short* w2f = w1f + 12 * 32 * 64 * 8;    // 131072
  unsigned short* w3f = w2f + 16 * 16 * 64 * 8;    // 49152
  unsigned short* whT = w3f + 8 * 12 * 64 * 8;     // 393216   (total ~1.54 MB)

  prep_kernel<<<376, 256, 0, stream>>>(W1, W2, W3, Wh, w1f, w2f, w3f, whT);
  fused_mlp<<<65536 / ROWS, THREADS, 0, stream>>>(x, b1, b2, b3, bh, W1, qid, corr,
                                                  w1f, w2f, w3f, whT, out);
}

// Round 5
// 106.133 us; speedup vs baseline: 1.3119x; 1.3119x over previous
//
#include <hip/hip_runtime.h>
#include <hip/hip_bf16.h>

#define THREADS 1024
#define ROWS 128

typedef __attribute__((ext_vector_type(4))) float f32x4;
typedef __attribute__((ext_vector_type(8))) short s16x8;

__device__ __forceinline__ unsigned short bfbits(float f) {
  __bf16 h = (__bf16)f;
  return __builtin_bit_cast(unsigned short, h);
}
__device__ __forceinline__ float bf2f(unsigned short h) {
  unsigned u = ((unsigned)h) << 16;
  return __builtin_bit_cast(float, u);
}

// ---------------- prep: pack weights into MFMA A-fragment order (bf16) ----------------
// A-frag for mfma_f32_16x16x32_bf16: lane l holds A[m=l&15][k=(l>>4)*8+j], j=0..7
// w1f: [c:12][ft:32][lane:64][8]   (K=384 of W1; k=384 is a rank-1 term in epilogue 1)
// w2f: [c:16][ft:16][lane:64][8]
// w3f: [c: 8][ft:12][lane:64][8]
// whT: [head:128][fo:24][j:16][8] bf16  (head gathers 256B-contiguous per 16-lane group)
__global__ void prep_kernel(const float* __restrict__ W1, const float* __restrict__ W2,
                            const float* __restrict__ W3, const float* __restrict__ Wh,
                            unsigned short* __restrict__ w1f, unsigned short* __restrict__ w2f,
                            unsigned short* __restrict__ w3f, unsigned short* __restrict__ whT) {
  int u = blockIdx.x * blockDim.x + threadIdx.x;
  const int U1 = 24576, U2 = 16384, U3 = 6144, U4 = 49152;
  if (u < U1) {                                   // W1 frags
    int lane = u & 63, r = (u >> 6) & 31, c = u >> 11;
    int f  = r * 16 + (lane & 15);
    int kb = c * 32 + ((lane >> 4) << 3);
    s16x8 v;
    #pragma unroll
    for (int j = 0; j < 8; ++j) v[j] = (short)bfbits(W1[(kb + j) * 512 + f]);
    *(s16x8*)(w1f + (u << 3)) = v;
    return;
  }
  u -= U1;
  if (u < U2) {                                   // W2 frags
    int lane = u & 63, r = (u >> 6) & 15, c = u >> 10;
    int f  = r * 16 + (lane & 15);
    int kb = c * 32 + ((lane >> 4) << 3);
    s16x8 v;
    #pragma unroll
    for (int j = 0; j < 8; ++j) v[j] = (short)bfbits(W2[(kb + j) * 256 + f]);
    *(s16x8*)(w2f + (u << 3)) = v;
    return;
  }
  u -= U2;
  if (u < U3) {                                   // W3 frags
    int lane = u & 63, t = u >> 6;
    int c = t / 12, r = t - c * 12;
    int f  = r * 16 + (lane & 15);
    int kb = c * 32 + ((lane >> 4) << 3);
    s16x8 v;
    #pragma unroll
    for (int j = 0; j < 8; ++j) v[j] = (short)bfbits(W3[(kb + j) * 192 + f]);
    *(s16x8*)(w3f + (u << 3)) = v;
    return;
  }
  u -= U3;
  if (u < U4) {                                   // Wh -> [head][fo][j][8]
    int j = u & 15, v2 = u >> 4;
    int fo = v2 % 24, head = v2 / 24;
    s16x8 v;
    #pragma unroll
    for (int i = 0; i < 8; ++i) v[i] = (short)bfbits(Wh[(fo * 8 + i) * 2048 + head * 16 + j]);
    *(s16x8*)(whT + u * 8) = v;
  }
}

// ---------------- fused MLP: 128 rows/block, 1024 threads, sequential-acc schedule ----------------
// LDS (163840 B = 160 KiB pool). Region rotation (no two accs co-resident):
//   @0      96K : xall (12 x-chunks)  ->  hL = h1 f256..511 frags (64K)  ->  h3b [128][200] bf16
//   @98304  64K : hH = h1 f0..255 frags  ->  h2f (GEMM3 B-frags)
// Biases / W1[384][:] / x[:,384] read straight from global (L1/L2-hot).
#define MFMA(a, b, c) __builtin_amdgcn_mfma_f32_16x16x32_bf16((a), (b), (c), 0, 0, 0)
#define SWZ(lp) (((lp) * 16) ^ ((((lp) >> 4) & 3) << 5))

#define G1_RANGE(P, C0, C1)                                                          \
  _Pragma("unroll")                                                                  \
  for (int c = (C0); c < (C1); ++c) {                                                \
    s16x8 af = *(const s16x8*)(w1f + (((c * 32 + (P) * 16 + w) * 64 + lane) << 3));  \
    _Pragma("unroll")                                                                \
    for (int bt = 0; bt < 8; ++bt) {                                                 \
      s16x8 bfr = *(const s16x8*)(xall + (c << 13) + (bt << 10) + swz_l);            \
      acc1[bt] = MFMA(af, bfr, acc1[bt]);                                            \
    }                                                                                \
  }

__global__ __launch_bounds__(THREADS, 4)
void fused_mlp(const float* __restrict__ x,
               const float* __restrict__ b1,
               const float* __restrict__ b2,
               const float* __restrict__ b3,
               const float* __restrict__ bh,
               const float* __restrict__ W1,
               const int* __restrict__ qid,
               const int* __restrict__ corr,
               const unsigned short* __restrict__ w1f,
               const unsigned short* __restrict__ w2f,
               const unsigned short* __restrict__ w3f,
               const unsigned short* __restrict__ whT,
               float* __restrict__ out) {
  __shared__ __align__(16) unsigned char lds[163840];
  unsigned char*  xall = lds;                             // GEMM1 B-frags (12 chunks)
  unsigned char*  hL   = lds;                             // h1 f256..511 frags (alias xall)
  unsigned short* h3b  = (unsigned short*)lds;            // [128][200] bf16 (alias, last)
  unsigned char*  hH   = lds + 98304;                     // h1 f0..255 frags
  unsigned char*  h2f  = lds + 98304;                     // GEMM3 B-frags (alias hH)

  const int tid  = threadIdx.x;
  const int lane = tid & 63;
  const int w    = tid >> 6;     // wave 0..15
  const int b0   = blockIdx.x * ROWS;
  const int l15  = lane & 15;
  const int lh   = lane >> 4;    // 0..3
  const int swz_l = SWZ(lane);

  // prefetch head routing + x[:,384] column (reused by both epilogue-1 passes)
  const int hrow = tid >> 4, hj = tid & 15;
  const int head0 = qid[b0 + hrow] * 2 + corr[b0 + hrow];
  const int head1 = qid[b0 + 64 + hrow] * 2 + corr[b0 + 64 + hrow];
  float xv384[8];
  #pragma unroll
  for (int bt = 0; bt < 8; ++bt)
    xv384[bt] = x[(size_t)(b0 + bt * 16 + l15) * 385 + 384];

  // ---- x staging: group g = chunks 4g..4g+3; 2 frags (16B) per thread per group ----
  f32x4 sv[2][2];
  int s_ad[2];
  auto sload = [&](int g) {
    #pragma unroll
    for (int q = 0; q < 2; ++q) {
      int fi = q * 1024 + tid;
      int c  = (g << 2) + (fi >> 9);
      int wi = fi & 511;
      int bt = wi >> 6, lp = wi & 63;
      int row = (bt << 4) + (lp & 15);
      int k   = c * 32 + ((lp >> 4) << 3);
      const float* p = x + (size_t)(b0 + row) * 385 + k;
      sv[q][0] = *(const f32x4*)p;
      sv[q][1] = *(const f32x4*)(p + 4);
      s_ad[q] = (c << 13) + (bt << 10) + SWZ(lp);
    }
  };
  auto swrite = [&]() {
    #pragma unroll
    for (int q = 0; q < 2; ++q) {
      s16x8 v;
      v[0] = (short)bfbits(sv[q][0][0]); v[1] = (short)bfbits(sv[q][0][1]);
      v[2] = (short)bfbits(sv[q][0][2]); v[3] = (short)bfbits(sv[q][0][3]);
      v[4] = (short)bfbits(sv[q][1][0]); v[5] = (short)bfbits(sv[q][1][1]);
      v[6] = (short)bfbits(sv[q][1][2]); v[7] = (short)bfbits(sv[q][1][3]);
      *(s16x8*)(xall + s_ad[q]) = v;
    }
  };

  f32x4 acc1[8];
  #pragma unroll
  for (int bt = 0; bt < 8; ++bt) acc1[bt] = (f32x4)0.0f;

  // epilogue 1 (pass P -> dst): rank-1 + bias + relu -> bf16 frags; reset acc1
  auto epi1 = [&](int P, unsigned char* dst) {
    int fg = P * 256 + w * 16 + lh * 4;
    f32x4 bv = *(const f32x4*)(b1 + fg);
    f32x4 wv = *(const f32x4*)(W1 + 384 * 512 + fg);
    int so = ((w >> 1) << 13) + SWZ(l15 + (((2 * w + (lh >> 1)) & 3) << 4)) + ((lh & 1) << 3);
    #pragma unroll
    for (int bt = 0; bt < 8; ++bt) {
      float xv = xv384[bt];
      float v0 = fmaxf(acc1[bt][0] + bv[0] + wv[0] * xv, 0.f);
      float v1 = fmaxf(acc1[bt][1] + bv[1] + wv[1] * xv, 0.f);
      float v2 = fmaxf(acc1[bt][2] + bv[2] + wv[2] * xv, 0.f);
      float v3 = fmaxf(acc1[bt][3] + bv[3] + wv[3] * xv, 0.f);
      unsigned plo = (unsigned)bfbits(v0) | ((unsigned)bfbits(v1) << 16);
      unsigned phi = (unsigned)bfbits(v2) | ((unsigned)bfbits(v3) << 16);
      unsigned long long pk = (unsigned long long)plo | ((unsigned long long)phi << 32);
      *(unsigned long long*)(dst + so + (bt << 10)) = pk;
      acc1[bt] = (f32x4)0.0f;
    }
  };

  // ---- GEMM1 pass 1 (f 0..255) pipelined with x staging ----
  sload(0); swrite();
  __syncthreads();                       // B1: chunks 0..3 staged

  sload(1);
  G1_RANGE(0, 0, 4)
  swrite();
  __syncthreads();                       // B2: chunks 4..7 staged

  sload(2);
  G1_RANGE(0, 4, 8)
  swrite();
  __syncthreads();                       // B3: chunks 8..11 staged

  G1_RANGE(0, 8, 12)
  epi1(0, hH);                           // h1 f0..255 -> hH (fresh region, no hazard)

  // ---- GEMM1 pass 2 (f 256..511); xall fully resident, no barriers inside ----
  G1_RANGE(1, 0, 12)
  __syncthreads();                       // B4: all xall reads done; hH writes visible
  epi1(1, hL);                           // h1 f256..511 -> hL (first 64K of dead xall)
  __syncthreads();                       // B5: hL visible

  // ---- GEMM2: h2^T[256f x 128b] = W2^T h1^T, K=512 (acc1 dead, acc2 born) ----
  f32x4 acc2[8];
  #pragma unroll
  for (int bt = 0; bt < 8; ++bt) acc2[bt] = (f32x4)0.0f;

  #pragma unroll
  for (int c = 0; c < 8; ++c) {
    s16x8 a2 = *(const s16x8*)(w2f + (((c * 16 + w) * 64 + lane) << 3));
    #pragma unroll
    for (int bt = 0; bt < 8; ++bt) {
      s16x8 bfr = *(const s16x8*)(hH + (c << 13) + (bt << 10) + swz_l);
      acc2[bt] = MFMA(a2, bfr, acc2[bt]);
    }
  }
  #pragma unroll
  for (int c = 8; c < 16; ++c) {
    s16x8 a2 = *(const s16x8*)(w2f + (((c * 16 + w) * 64 + lane) << 3));
    #pragma unroll
    for (int bt = 0; bt < 8; ++bt) {
      s16x8 bfr = *(const s16x8*)(hL + ((c - 8) << 13) + (bt << 10) + swz_l);
      acc2[bt] = MFMA(a2, bfr, acc2[bt]);
    }
  }
  __syncthreads();                       // B6: hH + hL reads done

  // epilogue 2 -> h2f (hH region)
  {
    int fg = w * 16 + lh * 4;
    f32x4 bv = *(const f32x4*)(b2 + fg);
    int so = ((w >> 1) << 13) + SWZ(l15 + (((2 * w + (lh >> 1)) & 3) << 4)) + ((lh & 1) << 3);
    #pragma unroll
    for (int bt = 0; bt < 8; ++bt) {
      float v0 = fmaxf(acc2[bt][0] + bv[0], 0.f);
      float v1 = fmaxf(acc2[bt][1] + bv[1], 0.f);
      float v2 = fmaxf(acc2[bt][2] + bv[2], 0.f);
      float v3 = fmaxf(acc2[bt][3] + bv[3], 0.f);
      unsigned plo = (unsigned)bfbits(v0) | ((unsigned)bfbits(v1) << 16);
      unsigned phi = (unsigned)bfbits(v2) | ((unsigned)bfbits(v3) << 16);
      unsigned long long pk = (unsigned long long)plo | ((unsigned long long)phi << 32);
      *(unsigned long long*)(h2f + so + (bt << 10)) = pk;
    }
  }
  __syncthreads();                       // B7: h2f visible

  // ---- GEMM3: h3^T[192f x 128b] = W3^T h2^T, K=256 (waves 0..11) ----
  if (w < 12) {
    f32x4 acc3[8];
    #pragma unroll
    for (int bt = 0; bt < 8; ++bt) acc3[bt] = (f32x4)0.0f;
    #pragma unroll
    for (int c = 0; c < 8; ++c) {
      s16x8 a3 = *(const s16x8*)(w3f + (((c * 12 + w) * 64 + lane) << 3));
      #pragma unroll
      for (int bt = 0; bt < 8; ++bt) {
        s16x8 bfr = *(const s16x8*)(h2f + (c << 13) + (bt << 10) + swz_l);
        acc3[bt] = MFMA(a3, bfr, acc3[bt]);
      }
    }
    // epilogue 3 -> h3b [128][200] bf16 (@0; region reads ended at B6)
    int fg = w * 16 + lh * 4;
    f32x4 bv = *(const f32x4*)(b3 + fg);
    #pragma unroll
    for (int bt = 0; bt < 8; ++bt) {
      int row = (bt << 4) + l15;
      float v0 = fmaxf(acc3[bt][0] + bv[0], 0.f);
      float v1 = fmaxf(acc3[bt][1] + bv[1], 0.f);
      float v2 = fmaxf(acc3[bt][2] + bv[2], 0.f);
      float v3 = fmaxf(acc3[bt][3] + bv[3], 0.f);
      unsigned plo = (unsigned)bfbits(v0) | ((unsigned)bfbits(v1) << 16);
      unsigned phi = (unsigned)bfbits(v2) | ((unsigned)bfbits(v3) << 16);
      unsigned long long pk = (unsigned long long)plo | ((unsigned long long)phi << 32);
      *(unsigned long long*)((unsigned char*)h3b + row * 400 + w * 32 + lh * 8) = pk;
    }
  }
  __syncthreads();                       // B8: h3b ready

  // ---- head: 2 outputs/thread ----
  #pragma unroll
  for (int q = 0; q < 2; ++q) {
    int row  = q * 64 + hrow;
    int head = q ? head1 : head0;
    const unsigned short* wp = whT + ((head * 24) * 16 + hj) * 8;
    const unsigned short* hp = h3b + row * 200;
    float acc = bh[(head << 4) + hj];
    #pragma unroll 6
    for (int fo = 0; fo < 24; ++fo) {
      s16x8 wv = *(const s16x8*)(wp + fo * 128);
      s16x8 hv = *(const s16x8*)(hp + fo * 8);
      #pragma unroll
      for (int e = 0; e < 8; ++e)
        acc += bf2f((unsigned short)wv[e]) * bf2f((unsigned short)hv[e]);
    }
    out[(size_t)(b0 + row) * 16 + hj] = acc;
  }
}

extern "C" void kernel_launch(void* const* d_in, const int* in_sizes, int n_in,
                              void* d_out, int out_size, void* d_ws, size_t ws_size,
                              hipStream_t stream) {
  (void)in_sizes; (void)n_in; (void)out_size; (void)ws_size;
  const float* x  = (const float*)d_in[0];
  const float* W1 = (const float*)d_in[1];
  const float* b1 = (const float*)d_in[2];
  const float* W2 = (const float*)d_in[3];
  const float* b2 = (const float*)d_in[4];
  const float* W3 = (const float*)d_in[5];
  const float* b3 = (const float*)d_in[6];
  const float* Wh = (const float*)d_in[7];
  const float* bh = (const float*)d_in[8];
  const int* qid  = (const int*)d_in[9];
  const int* corr = (const int*)d_in[10];
  float* out = (float*)d_out;

  unsigned short* w1f = (unsigned short*)d_ws;     // 196608 bf16
  unsigned short* w2f = w1f + 12 * 32 * 64 * 8;    // 131072
  unsigned short* w3f = w2f + 16 * 16 * 64 * 8;    // 49152
  unsigned short* whT = w3f + 8 * 12 * 64 * 8;     // 393216   (total ~1.54 MB)

  prep_kernel<<<376, 256, 0, stream>>>(W1, W2, W3, Wh, w1f, w2f, w3f, whT);
  fused_mlp<<<65536 / ROWS, THREADS, 0, stream>>>(x, b1, b2, b3, bh, W1, qid, corr,
                                                  w1f, w2f, w3f, whT, out);
}

// Round 6
// 103.400 us; speedup vs baseline: 1.3466x; 1.0264x over previous
//
#include <hip/hip_runtime.h>
#include <hip/hip_bf16.h>

#define THREADS 1024
#define ROWS 128

typedef __attribute__((ext_vector_type(4))) float f32x4;
typedef __attribute__((ext_vector_type(8))) short s16x8;

__device__ __forceinline__ unsigned short bfbits(float f) {
  __bf16 h = (__bf16)f;
  return __builtin_bit_cast(unsigned short, h);
}
__device__ __forceinline__ float bf2f(unsigned short h) {
  unsigned u = ((unsigned)h) << 16;
  return __builtin_bit_cast(float, u);
}

// ---------------- prep: pack weights into MFMA A-fragment order (bf16) ----------------
// A-frag for mfma_f32_16x16x32_bf16: lane l holds A[m=l&15][k=(l>>4)*8+j], j=0..7
// w1f: [c:12][ft:32][lane:64][8]   (K=384 of W1; k=384 is a rank-1 term in epilogue 1)
// w2f: [c:16][ft:16][lane:64][8]
// w3f: [c: 8][ft:12][lane:64][8]
// whT: [head:128][fo:24][j:16][8] bf16  (head gathers 256B-contiguous per 16-lane group)
__global__ void prep_kernel(const float* __restrict__ W1, const float* __restrict__ W2,
                            const float* __restrict__ W3, const float* __restrict__ Wh,
                            unsigned short* __restrict__ w1f, unsigned short* __restrict__ w2f,
                            unsigned short* __restrict__ w3f, unsigned short* __restrict__ whT) {
  int u = blockIdx.x * blockDim.x + threadIdx.x;
  const int U1 = 24576, U2 = 16384, U3 = 6144, U4 = 49152;
  if (u < U1) {                                   // W1 frags
    int lane = u & 63, r = (u >> 6) & 31, c = u >> 11;
    int f  = r * 16 + (lane & 15);
    int kb = c * 32 + ((lane >> 4) << 3);
    s16x8 v;
    #pragma unroll
    for (int j = 0; j < 8; ++j) v[j] = (short)bfbits(W1[(kb + j) * 512 + f]);
    *(s16x8*)(w1f + (u << 3)) = v;
    return;
  }
  u -= U1;
  if (u < U2) {                                   // W2 frags
    int lane = u & 63, r = (u >> 6) & 15, c = u >> 10;
    int f  = r * 16 + (lane & 15);
    int kb = c * 32 + ((lane >> 4) << 3);
    s16x8 v;
    #pragma unroll
    for (int j = 0; j < 8; ++j) v[j] = (short)bfbits(W2[(kb + j) * 256 + f]);
    *(s16x8*)(w2f + (u << 3)) = v;
    return;
  }
  u -= U2;
  if (u < U3) {                                   // W3 frags
    int lane = u & 63, t = u >> 6;
    int c = t / 12, r = t - c * 12;
    int f  = r * 16 + (lane & 15);
    int kb = c * 32 + ((lane >> 4) << 3);
    s16x8 v;
    #pragma unroll
    for (int j = 0; j < 8; ++j) v[j] = (short)bfbits(W3[(kb + j) * 192 + f]);
    *(s16x8*)(w3f + (u << 3)) = v;
    return;
  }
  u -= U3;
  if (u < U4) {                                   // Wh -> [head][fo][j][8]
    int j = u & 15, v2 = u >> 4;
    int fo = v2 % 24, head = v2 / 24;
    s16x8 v;
    #pragma unroll
    for (int i = 0; i < 8; ++i) v[i] = (short)bfbits(Wh[(fo * 8 + i) * 2048 + head * 16 + j]);
    *(s16x8*)(whT + u * 8) = v;
  }
}

// ---------------- fused MLP: 128 rows/block, 1024 threads, sequential-acc schedule ----------------
// LDS (163840 B = 160 KiB pool). Region rotation (no two accs co-resident):
//   @0      96K : xall (12 x-chunks)  ->  hL = h1 f256..511 frags (64K)  ->  h3b [128][200] bf16
//   @98304  64K : hH = h1 f0..255 frags  ->  h2f (GEMM3 B-frags)
// Arch-VGPR budget note: acc lives in AGPRs (64/64 split); staging is 1 frag/thread/group
// (8 data regs), no long-lived prefetch arrays -> arch side must stay < 64 (spill tripwire:
// WRITE_SIZE >> 4.2 MB).
#define MFMA(a, b, c) __builtin_amdgcn_mfma_f32_16x16x32_bf16((a), (b), (c), 0, 0, 0)
#define SWZ(lp) (((lp) * 16) ^ ((((lp) >> 4) & 3) << 5))

#define G1_RANGE(P, C0, C1)                                                          \
  _Pragma("unroll")                                                                  \
  for (int c = (C0); c < (C1); ++c) {                                                \
    s16x8 af = *(const s16x8*)(w1f + (((c * 32 + (P) * 16 + w) * 64 + lane) << 3));  \
    _Pragma("unroll")                                                                \
    for (int bt = 0; bt < 8; ++bt) {                                                 \
      s16x8 bfr = *(const s16x8*)(xall + (c << 13) + (bt << 10) + swz_l);            \
      acc1[bt] = MFMA(af, bfr, acc1[bt]);                                            \
    }                                                                                \
  }

__global__ __launch_bounds__(THREADS, 4)
void fused_mlp(const float* __restrict__ x,
               const float* __restrict__ b1,
               const float* __restrict__ b2,
               const float* __restrict__ b3,
               const float* __restrict__ bh,
               const float* __restrict__ W1,
               const int* __restrict__ qid,
               const int* __restrict__ corr,
               const unsigned short* __restrict__ w1f,
               const unsigned short* __restrict__ w2f,
               const unsigned short* __restrict__ w3f,
               const unsigned short* __restrict__ whT,
               float* __restrict__ out) {
  __shared__ __align__(16) unsigned char lds[163840];
  unsigned char*  xall = lds;                             // GEMM1 B-frags (12 chunks)
  unsigned char*  hL   = lds;                             // h1 f256..511 frags (alias xall)
  unsigned short* h3b  = (unsigned short*)lds;            // [128][200] bf16 (alias, last)
  unsigned char*  hH   = lds + 98304;                     // h1 f0..255 frags
  unsigned char*  h2f  = lds + 98304;                     // GEMM3 B-frags (alias hH)

  const int tid  = threadIdx.x;
  const int lane = tid & 63;
  const int w    = tid >> 6;     // wave 0..15
  const int b0   = blockIdx.x * ROWS;
  const int l15  = lane & 15;
  const int lh   = lane >> 4;    // 0..3
  const int swz_l = SWZ(lane);

  // ---- x staging: 6 groups x 2 chunks; ONE 16B frag per thread per group ----
  const int s_wi  = tid & 511;
  const int s_ci  = tid >> 9;                       // chunk parity in group
  const int s_bt  = s_wi >> 6;
  const int s_lp  = s_wi & 63;
  const float* s_base = x + (size_t)(b0 + (s_bt << 4) + (s_lp & 15)) * 385 + ((s_lp >> 4) << 3);
  const int s_abase = (s_bt << 10) + SWZ(s_lp);

  f32x4 sv0, sv1;
  auto sload = [&](int g) {
    int c = (g << 1) + s_ci;
    sv0 = *(const f32x4*)(s_base + c * 32);
    sv1 = *(const f32x4*)(s_base + c * 32 + 4);
  };
  auto swrite = [&](int g) {
    int c = (g << 1) + s_ci;
    s16x8 v;
    v[0] = (short)bfbits(sv0[0]); v[1] = (short)bfbits(sv0[1]);
    v[2] = (short)bfbits(sv0[2]); v[3] = (short)bfbits(sv0[3]);
    v[4] = (short)bfbits(sv1[0]); v[5] = (short)bfbits(sv1[1]);
    v[6] = (short)bfbits(sv1[2]); v[7] = (short)bfbits(sv1[3]);
    *(s16x8*)(xall + (c << 13) + s_abase) = v;
  };

  f32x4 acc1[8];
  #pragma unroll
  for (int bt = 0; bt < 8; ++bt) acc1[bt] = (f32x4)0.0f;

  // epilogue 1 (pass P -> dst): rank-1 + bias + relu -> bf16 frags; reset acc1
  auto epi1 = [&](int P, unsigned char* dst) {
    int fg = P * 256 + w * 16 + lh * 4;
    f32x4 bv = *(const f32x4*)(b1 + fg);
    f32x4 wv = *(const f32x4*)(W1 + 384 * 512 + fg);
    int so = ((w >> 1) << 13) + SWZ(l15 + (((2 * w + (lh >> 1)) & 3) << 4)) + ((lh & 1) << 3);
    #pragma unroll
    for (int bt = 0; bt < 8; ++bt) {
      float xv = x[(size_t)(b0 + (bt << 4) + l15) * 385 + 384];   // L1-hot rank-1 column
      float v0 = fmaxf(acc1[bt][0] + bv[0] + wv[0] * xv, 0.f);
      float v1 = fmaxf(acc1[bt][1] + bv[1] + wv[1] * xv, 0.f);
      float v2 = fmaxf(acc1[bt][2] + bv[2] + wv[2] * xv, 0.f);
      float v3 = fmaxf(acc1[bt][3] + bv[3] + wv[3] * xv, 0.f);
      unsigned plo = (unsigned)bfbits(v0) | ((unsigned)bfbits(v1) << 16);
      unsigned phi = (unsigned)bfbits(v2) | ((unsigned)bfbits(v3) << 16);
      unsigned long long pk = (unsigned long long)plo | ((unsigned long long)phi << 32);
      *(unsigned long long*)(dst + so + (bt << 10)) = pk;
      acc1[bt] = (f32x4)0.0f;
    }
  };

  // ---- GEMM1 pass 1 (f 0..255) pipelined with x staging (2 chunks/phase) ----
  sload(0); swrite(0);
  __syncthreads();                       // chunks 0..1 staged

  sload(1); G1_RANGE(0, 0, 2)  swrite(1); __syncthreads();
  sload(2); G1_RANGE(0, 2, 4)  swrite(2); __syncthreads();
  sload(3); G1_RANGE(0, 4, 6)  swrite(3); __syncthreads();
  sload(4); G1_RANGE(0, 6, 8)  swrite(4); __syncthreads();
  sload(5); G1_RANGE(0, 8, 10) swrite(5); __syncthreads();

  G1_RANGE(0, 10, 12)
  epi1(0, hH);                           // h1 f0..255 -> hH (fresh region, no hazard)

  // ---- GEMM1 pass 2 (f 256..511); xall fully resident, barrier-free ----
  G1_RANGE(1, 0, 12)
  __syncthreads();                       // all xall reads done; hH writes visible
  epi1(1, hL);                           // h1 f256..511 -> hL (first 64K of dead xall)
  __syncthreads();                       // hL visible

  // ---- GEMM2: h2^T[256f x 128b] = W2^T h1^T, K=512 (acc1 dead, acc2 born) ----
  f32x4 acc2[8];
  #pragma unroll
  for (int bt = 0; bt < 8; ++bt) acc2[bt] = (f32x4)0.0f;

  #pragma unroll
  for (int c = 0; c < 8; ++c) {
    s16x8 a2 = *(const s16x8*)(w2f + (((c * 16 + w) * 64 + lane) << 3));
    #pragma unroll
    for (int bt = 0; bt < 8; ++bt) {
      s16x8 bfr = *(const s16x8*)(hH + (c << 13) + (bt << 10) + swz_l);
      acc2[bt] = MFMA(a2, bfr, acc2[bt]);
    }
  }
  #pragma unroll
  for (int c = 8; c < 16; ++c) {
    s16x8 a2 = *(const s16x8*)(w2f + (((c * 16 + w) * 64 + lane) << 3));
    #pragma unroll
    for (int bt = 0; bt < 8; ++bt) {
      s16x8 bfr = *(const s16x8*)(hL + ((c - 8) << 13) + (bt << 10) + swz_l);
      acc2[bt] = MFMA(a2, bfr, acc2[bt]);
    }
  }
  __syncthreads();                       // hH + hL reads done

  // epilogue 2 -> h2f (hH region)
  {
    int fg = w * 16 + lh * 4;
    f32x4 bv = *(const f32x4*)(b2 + fg);
    int so = ((w >> 1) << 13) + SWZ(l15 + (((2 * w + (lh >> 1)) & 3) << 4)) + ((lh & 1) << 3);
    #pragma unroll
    for (int bt = 0; bt < 8; ++bt) {
      float v0 = fmaxf(acc2[bt][0] + bv[0], 0.f);
      float v1 = fmaxf(acc2[bt][1] + bv[1], 0.f);
      float v2 = fmaxf(acc2[bt][2] + bv[2], 0.f);
      float v3 = fmaxf(acc2[bt][3] + bv[3], 0.f);
      unsigned plo = (unsigned)bfbits(v0) | ((unsigned)bfbits(v1) << 16);
      unsigned phi = (unsigned)bfbits(v2) | ((unsigned)bfbits(v3) << 16);
      unsigned long long pk = (unsigned long long)plo | ((unsigned long long)phi << 32);
      *(unsigned long long*)(h2f + so + (bt << 10)) = pk;
    }
  }
  __syncthreads();                       // h2f visible

  // issue head-routing loads now; latency hides under GEMM3 + epilogue 3
  const int hrow = tid >> 4, hj = tid & 15;
  const int head0 = qid[b0 + hrow] * 2 + corr[b0 + hrow];
  const int head1 = qid[b0 + 64 + hrow] * 2 + corr[b0 + 64 + hrow];

  // ---- GEMM3: h3^T[192f x 128b] = W3^T h2^T, K=256 (waves 0..11) ----
  if (w < 12) {
    f32x4 acc3[8];
    #pragma unroll
    for (int bt = 0; bt < 8; ++bt) acc3[bt] = (f32x4)0.0f;
    #pragma unroll
    for (int c = 0; c < 8; ++c) {
      s16x8 a3 = *(const s16x8*)(w3f + (((c * 12 + w) * 64 + lane) << 3));
      #pragma unroll
      for (int bt = 0; bt < 8; ++bt) {
        s16x8 bfr = *(const s16x8*)(h2f + (c << 13) + (bt << 10) + swz_l);
        acc3[bt] = MFMA(a3, bfr, acc3[bt]);
      }
    }
    // epilogue 3 -> h3b [128][200] bf16 (@0; that region's last reads ended pre-epi2)
    int fg = w * 16 + lh * 4;
    f32x4 bv = *(const f32x4*)(b3 + fg);
    #pragma unroll
    for (int bt = 0; bt < 8; ++bt) {
      int row = (bt << 4) + l15;
      float v0 = fmaxf(acc3[bt][0] + bv[0], 0.f);
      float v1 = fmaxf(acc3[bt][1] + bv[1], 0.f);
      float v2 = fmaxf(acc3[bt][2] + bv[2], 0.f);
      float v3 = fmaxf(acc3[bt][3] + bv[3], 0.f);
      unsigned plo = (unsigned)bfbits(v0) | ((unsigned)bfbits(v1) << 16);
      unsigned phi = (unsigned)bfbits(v2) | ((unsigned)bfbits(v3) << 16);
      unsigned long long pk = (unsigned long long)plo | ((unsigned long long)phi << 32);
      *(unsigned long long*)((unsigned char*)h3b + row * 400 + w * 32 + lh * 8) = pk;
    }
  }
  __syncthreads();                       // h3b ready

  // ---- head: 2 outputs/thread ----
  #pragma unroll
  for (int q = 0; q < 2; ++q) {
    int row  = q * 64 + hrow;
    int head = q ? head1 : head0;
    const unsigned short* wp = whT + ((head * 24) * 16 + hj) * 8;
    const unsigned short* hp = h3b + row * 200;
    float acc = bh[(head << 4) + hj];
    #pragma unroll 6
    for (int fo = 0; fo < 24; ++fo) {
      s16x8 wv = *(const s16x8*)(wp + fo * 128);
      s16x8 hv = *(const s16x8*)(hp + fo * 8);
      #pragma unroll
      for (int e = 0; e < 8; ++e)
        acc += bf2f((unsigned short)wv[e]) * bf2f((unsigned short)hv[e]);
    }
    out[(size_t)(b0 + row) * 16 + hj] = acc;
  }
}

extern "C" void kernel_launch(void* const* d_in, const int* in_sizes, int n_in,
                              void* d_out, int out_size, void* d_ws, size_t ws_size,
                              hipStream_t stream) {
  (void)in_sizes; (void)n_in; (void)out_size; (void)ws_size;
  const float* x  = (const float*)d_in[0];
  const float* W1 = (const float*)d_in[1];
  const float* b1 = (const float*)d_in[2];
  const float* W2 = (const float*)d_in[3];
  const float* b2 = (const float*)d_in[4];
  const float* W3 = (const float*)d_in[5];
  const float* b3 = (const float*)d_in[6];
  const float* Wh = (const float*)d_in[7];
  const float* bh = (const float*)d_in[8];
  const int* qid  = (const int*)d_in[9];
  const int* corr = (const int*)d_in[10];
  float* out = (float*)d_out;

  unsigned short* w1f = (unsigned short*)d_ws;     // 196608 bf16
  unsigned short* w2f = w1f + 12 * 32 * 64 * 8;    // 131072
  unsigned short* w3f = w2f + 16 * 16 * 64 * 8;    // 49152
  unsigned short* whT = w3f + 8 * 12 * 64 * 8;     // 393216   (total ~1.54 MB)

  prep_kernel<<<376, 256, 0, stream>>>(W1, W2, W3, Wh, w1f, w2f, w3f, whT);
  fused_mlp<<<65536 / ROWS, THREADS, 0, stream>>>(x, b1, b2, b3, bh, W1, qid, corr,
                                                  w1f, w2f, w3f, whT, out);
}

// Round 7
// 92.427 us; speedup vs baseline: 1.5064x; 1.1187x over previous
//
#include <hip/hip_runtime.h>
#include <hip/hip_bf16.h>

#define THREADS 512
#define ROWS 64

typedef __attribute__((ext_vector_type(4))) float f32x4;
typedef __attribute__((ext_vector_type(8))) short s16x8;

__device__ __forceinline__ unsigned short bfbits(float f) {
  __bf16 h = (__bf16)f;
  return __builtin_bit_cast(unsigned short, h);
}
__device__ __forceinline__ float bf2f(unsigned short h) {
  unsigned u = ((unsigned)h) << 16;
  return __builtin_bit_cast(float, u);
}

// ---------------- prep: pack weights into MFMA A-fragment order (bf16) ----------------
// A-frag for mfma_f32_16x16x32_bf16: lane l holds A[m=l&15][k=(l>>4)*8+j], j=0..7
// w1f: [c:12][ft:32][lane:64][8]   (K=384 of W1; k=384 is a rank-1 term in epilogue 1)
// w2f: [c:16][ft:16][lane:64][8]
// w3f: [c: 8][ft:12][lane:64][8]
// whT: [head:128][fo:24][j:16][8] bf16
__global__ void prep_kernel(const float* __restrict__ W1, const float* __restrict__ W2,
                            const float* __restrict__ W3, const float* __restrict__ Wh,
                            unsigned short* __restrict__ w1f, unsigned short* __restrict__ w2f,
                            unsigned short* __restrict__ w3f, unsigned short* __restrict__ whT) {
  int u = blockIdx.x * blockDim.x + threadIdx.x;
  const int U1 = 24576, U2 = 16384, U3 = 6144, U4 = 49152;
  if (u < U1) {                                   // W1 frags
    int lane = u & 63, r = (u >> 6) & 31, c = u >> 11;
    int f  = r * 16 + (lane & 15);
    int kb = c * 32 + ((lane >> 4) << 3);
    s16x8 v;
    #pragma unroll
    for (int j = 0; j < 8; ++j) v[j] = (short)bfbits(W1[(kb + j) * 512 + f]);
    *(s16x8*)(w1f + (u << 3)) = v;
    return;
  }
  u -= U1;
  if (u < U2) {                                   // W2 frags
    int lane = u & 63, r = (u >> 6) & 15, c = u >> 10;
    int f  = r * 16 + (lane & 15);
    int kb = c * 32 + ((lane >> 4) << 3);
    s16x8 v;
    #pragma unroll
    for (int j = 0; j < 8; ++j) v[j] = (short)bfbits(W2[(kb + j) * 256 + f]);
    *(s16x8*)(w2f + (u << 3)) = v;
    return;
  }
  u -= U2;
  if (u < U3) {                                   // W3 frags
    int lane = u & 63, t = u >> 6;
    int c = t / 12, r = t - c * 12;
    int f  = r * 16 + (lane & 15);
    int kb = c * 32 + ((lane >> 4) << 3);
    s16x8 v;
    #pragma unroll
    for (int j = 0; j < 8; ++j) v[j] = (short)bfbits(W3[(kb + j) * 192 + f]);
    *(s16x8*)(w3f + (u << 3)) = v;
    return;
  }
  u -= U3;
  if (u < U4) {                                   // Wh -> [head][fo][j][8]
    int j = u & 15, v2 = u >> 4;
    int fo = v2 % 24, head = v2 / 24;
    s16x8 v;
    #pragma unroll
    for (int i = 0; i < 8; ++i) v[i] = (short)bfbits(Wh[(fo * 8 + i) * 2048 + head * 16 + j]);
    *(s16x8*)(whT + u * 8) = v;
  }
}

// ---------------- fused MLP: 64 rows/block, 512 threads, 2 blocks/CU ----------------
// LDS = 81920 B exactly -> two blocks fill the 160 KiB pool (independent barrier domains).
// Region rotation:
//   @0     48K : xall (12 x-chunks, [c][bt:4][lane':64][16B])
//                 -> h1L (h1 f256..511 frags, 32K) -> h3b [64][200] bf16 (25.6K)
//   @49152 32K : h1H (h1 f0..255 frags) -> h2f (GEMM3 B-frags)
// acc budget: two-f-pass GEMM1 keeps every accumulator at 32 AGPRs (sequential lifetimes);
// arch side ~55 -> total < 128-reg cap at 16 waves/CU. Spill tripwire: WRITE_SIZE >> 4.2 MB.
#define MFMA(a, b, c) __builtin_amdgcn_mfma_f32_16x16x32_bf16((a), (b), (c), 0, 0, 0)
#define SWZ(lp) (((lp) * 16) ^ ((((lp) >> 4) & 3) << 5))

#define G1_RANGE(P, C0, C1)                                                                 \
  _Pragma("unroll")                                                                         \
  for (int c = (C0); c < (C1); ++c) {                                                       \
    s16x8 a0 = *(const s16x8*)(w1f + (((c * 32 + (P) * 16 + w * 2 + 0) * 64 + lane) << 3)); \
    s16x8 a1 = *(const s16x8*)(w1f + (((c * 32 + (P) * 16 + w * 2 + 1) * 64 + lane) << 3)); \
    _Pragma("unroll")                                                                       \
    for (int bt = 0; bt < 4; ++bt) {                                                        \
      s16x8 bfr = *(const s16x8*)(xall + (c << 12) + (bt << 10) + swz_l);                   \
      acc1[0][bt] = MFMA(a0, bfr, acc1[0][bt]);                                             \
      acc1[1][bt] = MFMA(a1, bfr, acc1[1][bt]);                                             \
    }                                                                                       \
  }

__global__ __launch_bounds__(THREADS, 4)
void fused_mlp(const float* __restrict__ x,
               const float* __restrict__ b1,
               const float* __restrict__ b2,
               const float* __restrict__ b3,
               const float* __restrict__ bh,
               const float* __restrict__ W1,
               const int* __restrict__ qid,
               const int* __restrict__ corr,
               const unsigned short* __restrict__ w1f,
               const unsigned short* __restrict__ w2f,
               const unsigned short* __restrict__ w3f,
               const unsigned short* __restrict__ whT,
               float* __restrict__ out) {
  __shared__ __align__(16) unsigned char lds[81920];
  unsigned char*  xall = lds;                             // GEMM1 B-frags (12 x 4K)
  unsigned char*  h1L  = lds;                             // h1 f256..511 frags (alias xall)
  unsigned short* h3b  = (unsigned short*)lds;            // [64][200] bf16 (alias, last)
  unsigned char*  h1H  = lds + 49152;                     // h1 f0..255 frags (32K)
  unsigned char*  h2f  = lds + 49152;                     // GEMM3 B-frags (alias h1H)

  const int tid  = threadIdx.x;
  const int lane = tid & 63;
  const int w    = tid >> 6;     // wave 0..7
  const int b0   = blockIdx.x * ROWS;
  const int l15  = lane & 15;
  const int lh   = lane >> 4;    // 0..3
  const int swz_l = SWZ(lane);

  // ---- x staging: 6 groups x 2 chunks; ONE 16B frag per thread per group ----
  const int s_ci = tid >> 8;                       // chunk parity in group (0..1)
  const int s_wi = tid & 255;
  const int s_bt = s_wi >> 6;                      // 0..3
  const int s_lp = s_wi & 63;
  const float* s_base = x + (size_t)(b0 + (s_bt << 4) + (s_lp & 15)) * 385 + ((s_lp >> 4) << 3);
  const int s_abase = (s_bt << 10) + SWZ(s_lp);

  f32x4 sv0, sv1;
  auto sload = [&](int g) {
    int c = (g << 1) + s_ci;
    sv0 = *(const f32x4*)(s_base + c * 32);
    sv1 = *(const f32x4*)(s_base + c * 32 + 4);
  };
  auto swrite = [&](int g) {
    int c = (g << 1) + s_ci;
    s16x8 v;
    v[0] = (short)bfbits(sv0[0]); v[1] = (short)bfbits(sv0[1]);
    v[2] = (short)bfbits(sv0[2]); v[3] = (short)bfbits(sv0[3]);
    v[4] = (short)bfbits(sv1[0]); v[5] = (short)bfbits(sv1[1]);
    v[6] = (short)bfbits(sv1[2]); v[7] = (short)bfbits(sv1[3]);
    *(s16x8*)(xall + (c << 12) + s_abase) = v;
  };

  f32x4 acc1[2][4];
  #pragma unroll
  for (int a = 0; a < 2; ++a)
    #pragma unroll
    for (int bt = 0; bt < 4; ++bt) acc1[a][bt] = (f32x4)0.0f;

  // epilogue 1 (pass P -> dst): rank-1 (k=384) + bias + relu -> bf16 B-frags; reset acc1
  auto epi1 = [&](int P, unsigned char* dst) {
    #pragma unroll
    for (int a = 0; a < 2; ++a) {
      int ft = w * 2 + a;                           // f-tile within pass, 0..15
      int fg = P * 256 + (ft << 4) + (lh << 2);
      f32x4 bv = *(const f32x4*)(b1 + fg);
      f32x4 wv = *(const f32x4*)(W1 + 384 * 512 + fg);
      int so = ((ft >> 1) << 12) + SWZ(l15 + ((((ft & 1) << 1) + (lh >> 1)) << 4)) + ((lh & 1) << 3);
      #pragma unroll
      for (int bt = 0; bt < 4; ++bt) {
        float xv = x[(size_t)(b0 + (bt << 4) + l15) * 385 + 384];   // L1-hot rank-1 column
        float v0 = fmaxf(acc1[a][bt][0] + bv[0] + wv[0] * xv, 0.f);
        float v1 = fmaxf(acc1[a][bt][1] + bv[1] + wv[1] * xv, 0.f);
        float v2 = fmaxf(acc1[a][bt][2] + bv[2] + wv[2] * xv, 0.f);
        float v3 = fmaxf(acc1[a][bt][3] + bv[3] + wv[3] * xv, 0.f);
        unsigned plo = (unsigned)bfbits(v0) | ((unsigned)bfbits(v1) << 16);
        unsigned phi = (unsigned)bfbits(v2) | ((unsigned)bfbits(v3) << 16);
        unsigned long long pk = (unsigned long long)plo | ((unsigned long long)phi << 32);
        *(unsigned long long*)(dst + so + (bt << 10)) = pk;
        acc1[a][bt] = (f32x4)0.0f;
      }
    }
  };

  // ---- GEMM1 pass 1 (f 0..255) pipelined with x staging (2 chunks/phase) ----
  sload(0); swrite(0);
  __syncthreads();                       // chunks 0,1 staged

  sload(1); G1_RANGE(0, 0, 2)  swrite(1); __syncthreads();
  sload(2); G1_RANGE(0, 2, 4)  swrite(2); __syncthreads();
  sload(3); G1_RANGE(0, 4, 6)  swrite(3); __syncthreads();
  sload(4); G1_RANGE(0, 6, 8)  swrite(4); __syncthreads();
  sload(5); G1_RANGE(0, 8, 10) swrite(5); __syncthreads();

  G1_RANGE(0, 10, 12)
  epi1(0, h1H);                          // h1 f0..255 -> h1H (fresh region, no hazard)

  // ---- GEMM1 pass 2 (f 256..511); xall fully resident, barrier-free ----
  G1_RANGE(1, 0, 12)
  __syncthreads();                       // B7: all xall reads done; h1H writes visible
  epi1(1, h1L);                          // h1 f256..511 -> h1L (first 32K of dead xall)
  __syncthreads();                       // B8: h1L visible

  // ---- GEMM2: h2^T[256f x 64b] = W2^T h1^T, K=512 ----
  f32x4 acc2[2][4];
  #pragma unroll
  for (int i = 0; i < 2; ++i)
    #pragma unroll
    for (int bt = 0; bt < 4; ++bt) acc2[i][bt] = (f32x4)0.0f;

  #pragma unroll
  for (int c = 0; c < 16; ++c) {
    const unsigned char* reg = (c < 8) ? h1H : h1L;
    int cl = c & 7;
    s16x8 a20 = *(const s16x8*)(w2f + (((c * 16 + w * 2 + 0) * 64 + lane) << 3));
    s16x8 a21 = *(const s16x8*)(w2f + (((c * 16 + w * 2 + 1) * 64 + lane) << 3));
    #pragma unroll
    for (int bt = 0; bt < 4; ++bt) {
      s16x8 bfr = *(const s16x8*)(reg + (cl << 12) + (bt << 10) + swz_l);
      acc2[0][bt] = MFMA(a20, bfr, acc2[0][bt]);
      acc2[1][bt] = MFMA(a21, bfr, acc2[1][bt]);
    }
  }
  __syncthreads();                       // B9: h1H + h1L reads done

  // epilogue 2 -> h2f (h1H region)
  #pragma unroll
  for (int i = 0; i < 2; ++i) {
    int ft = w * 2 + i;
    int fg = (ft << 4) + (lh << 2);
    f32x4 bv = *(const f32x4*)(b2 + fg);
    int so = ((ft >> 1) << 12) + SWZ(l15 + ((((ft & 1) << 1) + (lh >> 1)) << 4)) + ((lh & 1) << 3);
    #pragma unroll
    for (int bt = 0; bt < 4; ++bt) {
      float v0 = fmaxf(acc2[i][bt][0] + bv[0], 0.f);
      float v1 = fmaxf(acc2[i][bt][1] + bv[1], 0.f);
      float v2 = fmaxf(acc2[i][bt][2] + bv[2], 0.f);
      float v3 = fmaxf(acc2[i][bt][3] + bv[3], 0.f);
      unsigned plo = (unsigned)bfbits(v0) | ((unsigned)bfbits(v1) << 16);
      unsigned phi = (unsigned)bfbits(v2) | ((unsigned)bfbits(v3) << 16);
      unsigned long long pk = (unsigned long long)plo | ((unsigned long long)phi << 32);
      *(unsigned long long*)(h2f + so + (bt << 10)) = pk;
    }
  }
  __syncthreads();                       // B10: h2f visible

  // head-routing loads issued now; latency hides under GEMM3 + epilogue 3
  const int hrow = tid >> 4, hj = tid & 15;
  const int head0 = qid[b0 + hrow] * 2 + corr[b0 + hrow];
  const int head1 = qid[b0 + 32 + hrow] * 2 + corr[b0 + 32 + hrow];

  // ---- GEMM3: h3^T[192f x 64b] = W3^T h2^T, K=256; 12 f-tiles over 8 waves ----
  {
    f32x4 acc3[2][4];
    #pragma unroll
    for (int i = 0; i < 2; ++i)
      #pragma unroll
      for (int bt = 0; bt < 4; ++bt) acc3[i][bt] = (f32x4)0.0f;

    #pragma unroll
    for (int c = 0; c < 8; ++c) {
      s16x8 a30 = *(const s16x8*)(w3f + (((c * 12 + w) * 64 + lane) << 3));
      s16x8 a31;
      if (w < 4) a31 = *(const s16x8*)(w3f + (((c * 12 + 8 + w) * 64 + lane) << 3));
      #pragma unroll
      for (int bt = 0; bt < 4; ++bt) {
        s16x8 bfr = *(const s16x8*)(h2f + (c << 12) + (bt << 10) + swz_l);
        acc3[0][bt] = MFMA(a30, bfr, acc3[0][bt]);
        if (w < 4) acc3[1][bt] = MFMA(a31, bfr, acc3[1][bt]);
      }
    }
    // epilogue 3 -> h3b [64][200] bf16 (@0; that region's reads ended at B9)
    #pragma unroll
    for (int i = 0; i < 2; ++i) {
      if (i == 0 || w < 4) {
        int ft = (i == 0) ? w : (8 + w);
        int fg = (ft << 4) + (lh << 2);
        f32x4 bv = *(const f32x4*)(b3 + fg);
        #pragma unroll
        for (int bt = 0; bt < 4; ++bt) {
          int row = (bt << 4) + l15;
          float v0 = fmaxf(acc3[i][bt][0] + bv[0], 0.f);
          float v1 = fmaxf(acc3[i][bt][1] + bv[1], 0.f);
          float v2 = fmaxf(acc3[i][bt][2] + bv[2], 0.f);
          float v3 = fmaxf(acc3[i][bt][3] + bv[3], 0.f);
          unsigned plo = (unsigned)bfbits(v0) | ((unsigned)bfbits(v1) << 16);
          unsigned phi = (unsigned)bfbits(v2) | ((unsigned)bfbits(v3) << 16);
          unsigned long long pk = (unsigned long long)plo | ((unsigned long long)phi << 32);
          *(unsigned long long*)((unsigned char*)h3b + row * 400 + (ft << 5) + (lh << 3)) = pk;
        }
      }
    }
  }
  __syncthreads();                       // B11: h3b ready

  // ---- head: 2 outputs/thread (rows hrow and 32+hrow) ----
  #pragma unroll
  for (int q = 0; q < 2; ++q) {
    int row  = q * 32 + hrow;
    int head = q ? head1 : head0;
    const unsigned short* wp = whT + ((head * 24) * 16 + hj) * 8;
    const unsigned short* hp = h3b + row * 200;
    float acc = bh[(head << 4) + hj];
    #pragma unroll 6
    for (int fo = 0; fo < 24; ++fo) {
      s16x8 wv = *(const s16x8*)(wp + fo * 128);
      s16x8 hv = *(const s16x8*)(hp + fo * 8);
      #pragma unroll
      for (int e = 0; e < 8; ++e)
        acc += bf2f((unsigned short)wv[e]) * bf2f((unsigned short)hv[e]);
    }
    out[(size_t)(b0 + row) * 16 + hj] = acc;
  }
}

extern "C" void kernel_launch(void* const* d_in, const int* in_sizes, int n_in,
                              void* d_out, int out_size, void* d_ws, size_t ws_size,
                              hipStream_t stream) {
  (void)in_sizes; (void)n_in; (void)out_size; (void)ws_size;
  const float* x  = (const float*)d_in[0];
  const float* W1 = (const float*)d_in[1];
  const float* b1 = (const float*)d_in[2];
  const float* W2 = (const float*)d_in[3];
  const float* b2 = (const float*)d_in[4];
  const float* W3 = (const float*)d_in[5];
  const float* b3 = (const float*)d_in[6];
  const float* Wh = (const float*)d_in[7];
  const float* bh = (const float*)d_in[8];
  const int* qid  = (const int*)d_in[9];
  const int* corr = (const int*)d_in[10];
  float* out = (float*)d_out;

  unsigned short* w1f = (unsigned short*)d_ws;     // 196608 bf16
  unsigned short* w2f = w1f + 12 * 32 * 64 * 8;    // 131072
  unsigned short* w3f = w2f + 16 * 16 * 64 * 8;    // 49152
  unsigned short* whT = w3f + 8 * 12 * 64 * 8;     // 393216   (total ~1.54 MB)

  prep_kernel<<<376, 256, 0, stream>>>(W1, W2, W3, Wh, w1f, w2f, w3f, whT);
  fused_mlp<<<65536 / ROWS, THREADS, 0, stream>>>(x, b1, b2, b3, bh, W1, qid, corr,
                                                  w1f, w2f, w3f, whT, out);
}